// Round 1
// 133.701 us; speedup vs baseline: 1.0433x; 1.0433x over previous
//
#include <hip/hip_runtime.h>
#include <cstdint>
#include <cstddef>

#define LOG2E 1.44269504088896340736f

typedef float  f32x16 __attribute__((ext_vector_type(16)));
typedef __bf16 bf16x8 __attribute__((ext_vector_type(8)));

union BF8 { bf16x8 v; uint u[4]; ushort us[8]; };

// pack two floats to bf16 pair (round-half-up), a -> lo16, b -> hi16
__device__ __forceinline__ uint pack_bf(float a, float b) {
    uint ua = __float_as_uint(a) + 0x8000u;
    uint ub = __float_as_uint(b) + 0x8000u;
    return __builtin_amdgcn_perm(ub, ua, 0x07060302u);
}
__device__ __forceinline__ float bf_lo(uint u) { return __uint_as_float(u << 16); }
__device__ __forceinline__ float bf_hi(uint u) { return __uint_as_float(u & 0xFFFF0000u); }

// ---------------------------------------------------------------------------
// convert_w: fp32 -> bf16 weights. qkv_w rows o<64 (=Q) pre-scaled 0.25*log2e.
// concat layout: qkv_w[49152] | c1w[32768] | out_w[16384] = 98304 elems.
// grid 96 x 256, one float4 per thread.
// ---------------------------------------------------------------------------
__global__ __launch_bounds__(256) void convert_w_kernel(
    const float* __restrict__ qkv_w, const float* __restrict__ c1w,
    const float* __restrict__ out_w,
    ushort* __restrict__ qkvw_b, ushort* __restrict__ c1w_b, ushort* __restrict__ ow_b)
{
    const int g = (blockIdx.x * 256 + threadIdx.x) * 4;
    const float* src; ushort* dst; int off; float sc = 1.f;
    if (g < 49152)      { src = qkv_w; dst = qkvw_b; off = g;
                          if (g < 16384) sc = 0.25f * LOG2E; }
    else if (g < 81920) { src = c1w;   dst = c1w_b;  off = g - 49152; }
    else                { src = out_w; dst = ow_b;   off = g - 81920; }
    float4 v = *(const float4*)(src + off);
    uint2 pk;
    pk.x = pack_bf(v.x * sc, v.y * sc);
    pk.y = pack_bf(v.z * sc, v.w * sc);
    *(uint2*)(dst + off) = pk;
}

// ---------------------------------------------------------------------------
// lnqkv: FUSED LayerNorm + QKV/conv MFMA GEMMs. One block = one 32-px group.
// Phase 1: per-px LayerNorm over 256 ch; xn (normalized) and xr (raw) land in
//   LDS in B-fragment-major layout [u=c/8][px][8ch] bf16 -> the MFMA loop's
//   B-load is a wave-contiguous ds_read_b128 (1 KB/wave, conflict-free).
// Phase 2: 4 waves: w0/1/2 = Q/K/V (2 tiles each, A=weights), w3 = conv
//   branch (4 tiles, B=xr) with relu*c2w reduction -> dynb.
// Epilogues via wave-private LDS transpose (stride 33, conflict-free).
// grid 256 x 256.
// ---------------------------------------------------------------------------
__global__ __launch_bounds__(256) void lnqkv_kernel(
    const float* __restrict__ x, const float* __restrict__ nw, const float* __restrict__ nb,
    const ushort* __restrict__ qkvw_b, const ushort* __restrict__ c1w_b,
    const float* __restrict__ c1b, const float* __restrict__ c2w,
    const float* __restrict__ c2b,
    ushort* __restrict__ Qb, ushort* __restrict__ Kb, ushort* __restrict__ Vsw,
    float* __restrict__ dynb)
{
    __shared__ uint  XN[32 * 32 * 4];      // [u][px][4 uint=8 bf16]  16 KB
    __shared__ uint  XR[32 * 32 * 4];      // raw x, same layout      16 KB
    __shared__ float trans[4][32 * 33];    //                         16.9 KB
    __shared__ float red1[256], red2[256];
    __shared__ float muS[32], rsS[32];

    const int t    = threadIdx.x;
    const int pg   = blockIdx.x;
    const int b    = pg >> 7;
    const int n0   = (pg & 127) * 32;

    // ------------------ Phase 1: LayerNorm into LDS ------------------
    {
        const int j  = t & 31;            // px
        const int cg = t >> 5;            // channel group (32 ch each)
        const size_t xb = (size_t)b * 256 * 4096 + n0 + j;
        float v[32];
        #pragma unroll
        for (int i = 0; i < 32; ++i) v[i] = x[xb + (size_t)(cg * 32 + i) * 4096];
        float s1 = 0.f, s2 = 0.f;
        #pragma unroll
        for (int i = 0; i < 32; ++i) { s1 += v[i]; s2 += v[i] * v[i]; }
        // raw x bf16 -> XR  (chunk u = cg*4+kk, px j); wave pattern is
        // 512B-sequential per 32-lane half -> conflict-free
        #pragma unroll
        for (int kk = 0; kk < 4; ++kk) {
            uint4 pk;
            pk.x = pack_bf(v[kk * 8 + 0], v[kk * 8 + 1]);
            pk.y = pack_bf(v[kk * 8 + 2], v[kk * 8 + 3]);
            pk.z = pack_bf(v[kk * 8 + 4], v[kk * 8 + 5]);
            pk.w = pack_bf(v[kk * 8 + 6], v[kk * 8 + 7]);
            *(uint4*)&XR[((cg * 4 + kk) * 32 + j) * 4] = pk;
        }
        red1[t] = s1; red2[t] = s2;
        __syncthreads();
        if (t < 32) {
            float a = 0.f, q = 0.f;
            #pragma unroll
            for (int g2 = 0; g2 < 8; ++g2) { a += red1[g2 * 32 + t]; q += red2[g2 * 32 + t]; }
            float mu  = a * (1.f / 256.f);
            float var = q * (1.f / 256.f) - mu * mu;
            muS[t] = mu; rsS[t] = rsqrtf(fmaxf(var, 0.f) + 1e-5f);
        }
        __syncthreads();
        const float mu = muS[j], rs = rsS[j];
        #pragma unroll
        for (int kk = 0; kk < 4; ++kk) {
            const float4 w0 = *(const float4*)(nw + cg * 32 + kk * 8);
            const float4 w1 = *(const float4*)(nw + cg * 32 + kk * 8 + 4);
            const float4 b0 = *(const float4*)(nb + cg * 32 + kk * 8);
            const float4 b1 = *(const float4*)(nb + cg * 32 + kk * 8 + 4);
            float e0 = (v[kk * 8 + 0] - mu) * rs * w0.x + b0.x;
            float e1 = (v[kk * 8 + 1] - mu) * rs * w0.y + b0.y;
            float e2 = (v[kk * 8 + 2] - mu) * rs * w0.z + b0.z;
            float e3 = (v[kk * 8 + 3] - mu) * rs * w0.w + b0.w;
            float e4 = (v[kk * 8 + 4] - mu) * rs * w1.x + b1.x;
            float e5 = (v[kk * 8 + 5] - mu) * rs * w1.y + b1.y;
            float e6 = (v[kk * 8 + 6] - mu) * rs * w1.z + b1.z;
            float e7 = (v[kk * 8 + 7] - mu) * rs * w1.w + b1.w;
            uint4 o;
            o.x = pack_bf(e0, e1); o.y = pack_bf(e2, e3);
            o.z = pack_bf(e4, e5); o.w = pack_bf(e6, e7);
            *(uint4*)&XN[((cg * 4 + kk) * 32 + j) * 4] = o;
        }
    }
    __syncthreads();

    // ------------------ Phase 2: MFMA GEMMs from LDS ------------------
    const int w    = t >> 6;
    const int lane = t & 63;
    const int m    = lane & 31;       // A-row / C-col index (= px for B)
    const int h    = lane >> 5;       // k-slot half
    float* tr = trans[w];
    const ushort* xnB = (const ushort*)XN;
    const ushort* xrB = (const ushort*)XR;

    if (w < 3) {
        const ushort* ap0 = qkvw_b + ((size_t)(w * 64 + m)) * 256 + h * 8;
        const ushort* ap1 = ap0 + 32 * 256;
        f32x16 acc0, acc1;
        #pragma unroll
        for (int i = 0; i < 16; ++i) { acc0[i] = 0.f; acc1[i] = 0.f; }
        #pragma unroll 4
        for (int ks = 0; ks < 16; ++ks) {
            bf16x8 bf = *(const bf16x8*)(xnB + ((ks * 2 + h) * 32 + m) * 8);
            bf16x8 a0 = *(const bf16x8*)(ap0 + ks * 16);
            bf16x8 a1 = *(const bf16x8*)(ap1 + ks * 16);
            acc0 = __builtin_amdgcn_mfma_f32_32x32x16_bf16(a0, bf, acc0, 0, 0, 0);
            acc1 = __builtin_amdgcn_mfma_f32_32x32x16_bf16(a1, bf, acc1, 0, 0, 0);
        }
        for (int ti = 0; ti < 2; ++ti) {
            const f32x16& A = ti ? acc1 : acc0;
            #pragma unroll
            for (int r = 0; r < 16; ++r)
                tr[((r & 3) + 8 * (r >> 2) + 4 * h) * 33 + m] = A[r];
            if (w < 2) {
                ushort* dst = (w == 0) ? Qb : Kb;
                #pragma unroll
                for (int it = 0; it < 2; ++it) {
                    int unit = it * 2 + h;            // 0..3
                    int hl = unit >> 1, half = unit & 1;
                    float v0 = tr[(hl * 16 + half * 8 + 0) * 33 + m];
                    float v1 = tr[(hl * 16 + half * 8 + 1) * 33 + m];
                    float v2 = tr[(hl * 16 + half * 8 + 2) * 33 + m];
                    float v3 = tr[(hl * 16 + half * 8 + 3) * 33 + m];
                    float v4 = tr[(hl * 16 + half * 8 + 4) * 33 + m];
                    float v5 = tr[(hl * 16 + half * 8 + 5) * 33 + m];
                    float v6 = tr[(hl * 16 + half * 8 + 6) * 33 + m];
                    float v7 = tr[(hl * 16 + half * 8 + 7) * 33 + m];
                    uint4 pk;
                    pk.x = pack_bf(v0, v1); pk.y = pack_bf(v2, v3);
                    pk.z = pack_bf(v4, v5); pk.w = pack_bf(v6, v7);
                    int head = ti * 2 + hl;
                    *(uint4*)(dst + ((size_t)(b * 4 + head) * 4096 + n0 + m) * 16 + half * 8) = pk;
                }
            } else {
                int d = lane & 15, u = lane >> 4;
                #pragma unroll
                for (int it = 0; it < 4; ++it) {
                    int unit = it * 4 + u;            // 0..15
                    int hl = unit >> 3, sg = unit & 7;
                    float v0 = tr[(hl * 16 + d) * 33 + sg * 4 + 0];
                    float v1 = tr[(hl * 16 + d) * 33 + sg * 4 + 1];
                    float v2 = tr[(hl * 16 + d) * 33 + sg * 4 + 2];
                    float v3 = tr[(hl * 16 + d) * 33 + sg * 4 + 3];
                    uint2 pk; pk.x = pack_bf(v0, v1); pk.y = pack_bf(v2, v3);
                    int head = ti * 2 + hl;
                    *(uint2*)(Vsw + (((size_t)(b * 4 + head) * 1024 + (pg & 127) * 8 + sg) * 16 + d) * 4) = pk;
                }
            }
        }
    } else {
        // conv branch: 4 tiles x 16 ksteps on raw x (from LDS)
        f32x16 acc[4];
        #pragma unroll
        for (int ti = 0; ti < 4; ++ti)
            #pragma unroll
            for (int i = 0; i < 16; ++i) acc[ti][i] = 0.f;
        #pragma unroll 2
        for (int ks = 0; ks < 16; ++ks) {
            bf16x8 bf = *(const bf16x8*)(xrB + ((ks * 2 + h) * 32 + m) * 8);
            #pragma unroll
            for (int ti = 0; ti < 4; ++ti) {
                bf16x8 a = *(const bf16x8*)(c1w_b + ((size_t)(ti * 32 + m)) * 256 + ks * 16 + h * 8);
                acc[ti] = __builtin_amdgcn_mfma_f32_32x32x16_bf16(a, bf, acc[ti], 0, 0, 0);
            }
        }
        float partial = 0.f;
        for (int ti = 0; ti < 4; ++ti) {
            #pragma unroll
            for (int r = 0; r < 16; ++r)
                tr[((r & 3) + 8 * (r >> 2) + 4 * h) * 33 + m] = acc[ti][r];
            #pragma unroll
            for (int i = 0; i < 16; ++i) {
                int og = ti * 32 + h * 16 + i;
                partial += fmaxf(tr[(h * 16 + i) * 33 + m] + c1b[og], 0.f) * c2w[og];
            }
        }
        float tot = partial + __shfl_xor(partial, 32);
        if (lane < 32) dynb[(size_t)b * 4096 + n0 + m] = c2b[0] + tot;
    }
}

// ---------------------------------------------------------------------------
// attn: MFMA flash attention (unchanged core). Epilogue writes AO2 rows
// [kb*8+bh][n][20]: d0..15 at 0..15, l at 16. grid 512 x 256.
// ---------------------------------------------------------------------------
__global__ __launch_bounds__(256) void attn_kernel(
    const ushort* __restrict__ Qb, const ushort* __restrict__ Kb,
    const ushort* __restrict__ Vsw, float* __restrict__ AO2)
{
    const int t   = threadIdx.x;
    const int lid = t & 63;
    const int w   = t >> 6;
    const int c   = lid & 31;
    const int h   = lid >> 5;

    const int bi = blockIdx.x;
    const int kb = bi & 1;
    const int qb = (bi >> 1) & 31;
    const int bh = bi >> 6;
    const int nq = qb * 128 + w * 32;

    const bf16x8 qf = *(const bf16x8*)(Qb + ((size_t)bh * 4096 + nq + c) * 16 + h * 8);

    f32x16 oacc, zf;
    #pragma unroll
    for (int i = 0; i < 16; ++i) { oacc[i] = 0.f; zf[i] = 0.f; }

    const ushort* kp = Kb + ((size_t)bh * 4096 + kb * 2048 + c) * 16 + h * 8;
    const ushort* vb = Vsw + (size_t)bh * 65536 + ((size_t)kb * 512 + h) * 64 + c * 4;

    #pragma unroll 2
    for (int ch = 0; ch < 64; ++ch) {
        const bf16x8 kf = *(const bf16x8*)kp;
        f32x16 s = __builtin_amdgcn_mfma_f32_32x32x16_bf16(kf, qf, zf, 0, 0, 0);

        BF8 p1, p2;
        #pragma unroll
        for (int jj = 0; jj < 4; ++jj) {
            p1.u[jj] = pack_bf(__builtin_amdgcn_exp2f(s[2*jj]),   __builtin_amdgcn_exp2f(s[2*jj+1]));
            p2.u[jj] = pack_bf(__builtin_amdgcn_exp2f(s[8+2*jj]), __builtin_amdgcn_exp2f(s[8+2*jj+1]));
        }

        BF8 a1, a2;
        if (c < 16) {
            const uint2 g1 = *(const uint2*)(vb);
            const uint2 g2 = *(const uint2*)(vb + 128);
            const uint2 g3 = *(const uint2*)(vb + 256);
            const uint2 g4 = *(const uint2*)(vb + 384);
            a1.u[0] = g1.x; a1.u[1] = g1.y; a1.u[2] = g2.x; a1.u[3] = g2.y;
            a2.u[0] = g3.x; a2.u[1] = g3.y; a2.u[2] = g4.x; a2.u[3] = g4.y;
        } else {
            const uint f = (c == 16) ? 0x3F803F80u : 0u;   // ones row -> l
            a1.u[0] = a1.u[1] = a1.u[2] = a1.u[3] = f;
            a2.u[0] = a2.u[1] = a2.u[2] = a2.u[3] = f;
        }

        oacc = __builtin_amdgcn_mfma_f32_32x32x16_bf16(a1.v, p1.v, oacc, 0, 0, 0);
        oacc = __builtin_amdgcn_mfma_f32_32x32x16_bf16(a2.v, p2.v, oacc, 0, 0, 0);

        kp += 512; vb += 512;
    }

    float* ao = AO2 + ((size_t)(kb * 8 + bh) * 4096 + nq + c) * 20;
    float4 s0; s0.x = oacc[0]; s0.y = oacc[1]; s0.z = oacc[2]; s0.w = oacc[3];
    float4 s1; s1.x = oacc[4]; s1.y = oacc[5]; s1.z = oacc[6]; s1.w = oacc[7];
    *(float4*)(ao + 4 * h)     = s0;     // d {0..3}+4h
    *(float4*)(ao + 8 + 4 * h) = s1;     // d {8..11}+4h
    if (h == 0) ao[16] = oacc[8];        // l
}

// ---------------------------------------------------------------------------
// final: MFMA out-proj. Per kstep ks (=head), lanes build B-frag from AO2
// (merge kb splits, /l, *dyn). A = out_w bf16. Epilogue via LDS transpose ->
// coalesced sigmoid(g*y + x) writes. grid 256 x 256.
// ---------------------------------------------------------------------------
__global__ __launch_bounds__(256) void final_kernel(
    const float* __restrict__ AO2, const float* __restrict__ dynb,
    const ushort* __restrict__ ow_b, const float* __restrict__ x,
    const float* __restrict__ gamma, float* __restrict__ out)
{
    __shared__ float trans[4][32 * 33];
    const int t    = threadIdx.x;
    const int w    = t >> 6;
    const int lane = t & 63;
    const int m    = lane & 31;      // px / A-row
    const int h    = lane >> 5;
    const int pg   = blockIdx.x;
    const int b    = pg >> 7;
    const int n0   = (pg & 127) * 32;
    float* tr = trans[w];

    const float dyn_px = dynb[(size_t)b * 4096 + n0 + m];
    const ushort* a0p = ow_b + ((size_t)(w * 64 + m)) * 64 + h * 8;
    const ushort* a1p = a0p + 32 * 64;

    f32x16 acc0, acc1;
    #pragma unroll
    for (int i = 0; i < 16; ++i) { acc0[i] = 0.f; acc1[i] = 0.f; }

    #pragma unroll
    for (int ks = 0; ks < 4; ++ks) {
        const float* r0 = AO2 + ((size_t)(b * 4 + ks) * 4096 + n0 + m) * 20;
        const float* r1 = r0 + (size_t)8 * 4096 * 20;
        float l   = r0[16] + r1[16];
        float fac = dyn_px / l;
        float4 u0 = *(const float4*)(r0 + h * 8);
        float4 u1 = *(const float4*)(r0 + h * 8 + 4);
        float4 t0 = *(const float4*)(r1 + h * 8);
        float4 t1 = *(const float4*)(r1 + h * 8 + 4);
        float e0 = (u0.x + t0.x) * fac, e1 = (u0.y + t0.y) * fac;
        float e2 = (u0.z + t0.z) * fac, e3 = (u0.w + t0.w) * fac;
        float e4 = (u1.x + t1.x) * fac, e5 = (u1.y + t1.y) * fac;
        float e6 = (u1.z + t1.z) * fac, e7 = (u1.w + t1.w) * fac;
        BF8 bfr;
        bfr.u[0] = pack_bf(e0, e1); bfr.u[1] = pack_bf(e2, e3);
        bfr.u[2] = pack_bf(e4, e5); bfr.u[3] = pack_bf(e6, e7);
        bf16x8 af0 = *(const bf16x8*)(a0p + ks * 16);
        bf16x8 af1 = *(const bf16x8*)(a1p + ks * 16);
        acc0 = __builtin_amdgcn_mfma_f32_32x32x16_bf16(af0, bfr.v, acc0, 0, 0, 0);
        acc1 = __builtin_amdgcn_mfma_f32_32x32x16_bf16(af1, bfr.v, acc1, 0, 0, 0);
    }

    const float g = gamma[0];
    for (int ti = 0; ti < 2; ++ti) {
        const f32x16& A = ti ? acc1 : acc0;
        #pragma unroll
        for (int r = 0; r < 16; ++r)
            tr[((r & 3) + 8 * (r >> 2) + 4 * h) * 33 + m] = A[r];
        int ob = w * 64 + ti * 32;
        #pragma unroll 4
        for (int it = 0; it < 16; ++it) {
            int o = it * 2 + h;
            float vv = tr[o * 33 + m];
            size_t idx = ((size_t)b * 256 + ob + o) * 4096 + n0 + m;
            float z = g * vv + x[idx];
            out[idx] = 1.f / (1.f + __builtin_amdgcn_exp2f(-z * LOG2E));
        }
    }
}

// ---------------------------------------------------------------------------
extern "C" void kernel_launch(void* const* d_in, const int* in_sizes, int n_in,
                              void* d_out, int out_size, void* d_ws, size_t ws_size,
                              hipStream_t stream)
{
    const float* x      = (const float*)d_in[0];
    const float* norm_w = (const float*)d_in[1];
    const float* norm_b = (const float*)d_in[2];
    const float* qkv_w  = (const float*)d_in[3];
    const float* out_w  = (const float*)d_in[4];
    const float* c1w    = (const float*)d_in[5];
    const float* c1b    = (const float*)d_in[6];
    const float* c2w    = (const float*)d_in[7];
    const float* c2b    = (const float*)d_in[8];
    const float* gamma  = (const float*)d_in[9];

    char* ws = (char*)d_ws;
    ushort* Qb     = (ushort*)ws;                       // 524288 ush (1 MB)
    ushort* Kb     = Qb + 524288;
    ushort* Vsw    = Kb + 524288;                       // 524288 ush
    ushort* qkvw_b = Vsw + 524288;                      // 49152
    ushort* c1w_b  = qkvw_b + 49152;                    // 32768
    ushort* ow_b   = c1w_b + 32768;                     // 16384
    float*  dynb   = (float*)(ws + 3342336);            // 8192 floats
    float*  AO2    = (float*)(ws + 3375104);            // 2*8*4096*20 fp32 (5.24 MB)

    hipLaunchKernelGGL(convert_w_kernel, dim3(96), dim3(256), 0, stream,
                       qkv_w, c1w, out_w, qkvw_b, c1w_b, ow_b);
    hipLaunchKernelGGL(lnqkv_kernel, dim3(256), dim3(256), 0, stream,
                       x, norm_w, norm_b, qkvw_b, c1w_b, c1b, c2w, c2b,
                       Qb, Kb, Vsw, dynb);
    hipLaunchKernelGGL(attn_kernel, dim3(512), dim3(256), 0, stream,
                       Qb, Kb, Vsw, AO2);
    hipLaunchKernelGGL(final_kernel, dim3(256), dim3(256), 0, stream,
                       AO2, dynb, ow_b, x, gamma, (float*)d_out);
}

// Round 2
// 125.167 us; speedup vs baseline: 1.1144x; 1.0682x over previous
//
#include <hip/hip_runtime.h>
#include <cstdint>
#include <cstddef>

#define LOG2E 1.44269504088896340736f

typedef float  f32x16 __attribute__((ext_vector_type(16)));
typedef __bf16 bf16x8 __attribute__((ext_vector_type(8)));

union BF8 { bf16x8 v; uint u[4]; ushort us[8]; };

// pack two floats to bf16 pair (round-half-up), a -> lo16, b -> hi16
__device__ __forceinline__ uint pack_bf(float a, float b) {
    uint ua = __float_as_uint(a) + 0x8000u;
    uint ub = __float_as_uint(b) + 0x8000u;
    return __builtin_amdgcn_perm(ub, ua, 0x07060302u);
}
__device__ __forceinline__ float bf_lo(uint u) { return __uint_as_float(u << 16); }
__device__ __forceinline__ float bf_hi(uint u) { return __uint_as_float(u & 0xFFFF0000u); }

// ---------------------------------------------------------------------------
// convert_w: fp32 -> bf16 weights. qkv_w rows o<64 (=Q) pre-scaled 0.25*log2e.
// concat layout: qkv_w[49152] | c1w[32768] | out_w[16384] = 98304 elems.
// grid 96 x 256, one float4 per thread.
// ---------------------------------------------------------------------------
__global__ __launch_bounds__(256) void convert_w_kernel(
    const float* __restrict__ qkv_w, const float* __restrict__ c1w,
    const float* __restrict__ out_w,
    ushort* __restrict__ qkvw_b, ushort* __restrict__ c1w_b, ushort* __restrict__ ow_b)
{
    const int g = (blockIdx.x * 256 + threadIdx.x) * 4;
    const float* src; ushort* dst; int off; float sc = 1.f;
    if (g < 49152)      { src = qkv_w; dst = qkvw_b; off = g;
                          if (g < 16384) sc = 0.25f * LOG2E; }
    else if (g < 81920) { src = c1w;   dst = c1w_b;  off = g - 49152; }
    else                { src = out_w; dst = ow_b;   off = g - 81920; }
    float4 v = *(const float4*)(src + off);
    uint2 pk;
    pk.x = pack_bf(v.x * sc, v.y * sc);
    pk.y = pack_bf(v.z * sc, v.w * sc);
    *(uint2*)(dst + off) = pk;
}

// ---------------------------------------------------------------------------
// lnqkv: FUSED LayerNorm + QKV/conv MFMA GEMMs. One block = one 32-px group.
// Phase 1: per-px LayerNorm over 256 ch; xn (normalized) and xr (raw) land in
//   LDS in B-fragment-major layout [u=c/8][px][8ch] bf16 -> the MFMA loop's
//   B-load is a wave-contiguous ds_read_b128 (1 KB/wave, conflict-free).
// Phase 2: 4 waves: w0/1/2 = Q/K/V (2 tiles each, A=weights), w3 = conv
//   branch (4 tiles, B=xr) with relu*c2w reduction -> dynb.
// Epilogues via wave-private LDS transpose (stride 33, conflict-free).
// grid 256 x 256.
// ---------------------------------------------------------------------------
__global__ __launch_bounds__(256) void lnqkv_kernel(
    const float* __restrict__ x, const float* __restrict__ nw, const float* __restrict__ nb,
    const ushort* __restrict__ qkvw_b, const ushort* __restrict__ c1w_b,
    const float* __restrict__ c1b, const float* __restrict__ c2w,
    const float* __restrict__ c2b,
    ushort* __restrict__ Qb, ushort* __restrict__ Kb, ushort* __restrict__ Vsw,
    float* __restrict__ dynb)
{
    __shared__ uint  XN[32 * 32 * 4];      // [u][px][4 uint=8 bf16]  16 KB
    __shared__ uint  XR[32 * 32 * 4];      // raw x, same layout      16 KB
    __shared__ float trans[4][32 * 33];    //                         16.9 KB
    __shared__ float red1[256], red2[256];
    __shared__ float muS[32], rsS[32];

    const int t    = threadIdx.x;
    const int pg   = blockIdx.x;
    const int b    = pg >> 7;
    const int n0   = (pg & 127) * 32;

    // ------------------ Phase 1: LayerNorm into LDS ------------------
    {
        const int j  = t & 31;            // px
        const int cg = t >> 5;            // channel group (32 ch each)
        const size_t xb = (size_t)b * 256 * 4096 + n0 + j;
        float v[32];
        #pragma unroll
        for (int i = 0; i < 32; ++i) v[i] = x[xb + (size_t)(cg * 32 + i) * 4096];
        float s1 = 0.f, s2 = 0.f;
        #pragma unroll
        for (int i = 0; i < 32; ++i) { s1 += v[i]; s2 += v[i] * v[i]; }
        // raw x bf16 -> XR  (chunk u = cg*4+kk, px j); wave pattern is
        // 512B-sequential per 32-lane half -> conflict-free
        #pragma unroll
        for (int kk = 0; kk < 4; ++kk) {
            uint4 pk;
            pk.x = pack_bf(v[kk * 8 + 0], v[kk * 8 + 1]);
            pk.y = pack_bf(v[kk * 8 + 2], v[kk * 8 + 3]);
            pk.z = pack_bf(v[kk * 8 + 4], v[kk * 8 + 5]);
            pk.w = pack_bf(v[kk * 8 + 6], v[kk * 8 + 7]);
            *(uint4*)&XR[((cg * 4 + kk) * 32 + j) * 4] = pk;
        }
        red1[t] = s1; red2[t] = s2;
        __syncthreads();
        if (t < 32) {
            float a = 0.f, q = 0.f;
            #pragma unroll
            for (int g2 = 0; g2 < 8; ++g2) { a += red1[g2 * 32 + t]; q += red2[g2 * 32 + t]; }
            float mu  = a * (1.f / 256.f);
            float var = q * (1.f / 256.f) - mu * mu;
            muS[t] = mu; rsS[t] = rsqrtf(fmaxf(var, 0.f) + 1e-5f);
        }
        __syncthreads();
        const float mu = muS[j], rs = rsS[j];
        #pragma unroll
        for (int kk = 0; kk < 4; ++kk) {
            const float4 w0 = *(const float4*)(nw + cg * 32 + kk * 8);
            const float4 w1 = *(const float4*)(nw + cg * 32 + kk * 8 + 4);
            const float4 b0 = *(const float4*)(nb + cg * 32 + kk * 8);
            const float4 b1 = *(const float4*)(nb + cg * 32 + kk * 8 + 4);
            float e0 = (v[kk * 8 + 0] - mu) * rs * w0.x + b0.x;
            float e1 = (v[kk * 8 + 1] - mu) * rs * w0.y + b0.y;
            float e2 = (v[kk * 8 + 2] - mu) * rs * w0.z + b0.z;
            float e3 = (v[kk * 8 + 3] - mu) * rs * w0.w + b0.w;
            float e4 = (v[kk * 8 + 4] - mu) * rs * w1.x + b1.x;
            float e5 = (v[kk * 8 + 5] - mu) * rs * w1.y + b1.y;
            float e6 = (v[kk * 8 + 6] - mu) * rs * w1.z + b1.z;
            float e7 = (v[kk * 8 + 7] - mu) * rs * w1.w + b1.w;
            uint4 o;
            o.x = pack_bf(e0, e1); o.y = pack_bf(e2, e3);
            o.z = pack_bf(e4, e5); o.w = pack_bf(e6, e7);
            *(uint4*)&XN[((cg * 4 + kk) * 32 + j) * 4] = o;
        }
    }
    __syncthreads();

    // ------------------ Phase 2: MFMA GEMMs from LDS ------------------
    const int w    = t >> 6;
    const int lane = t & 63;
    const int m    = lane & 31;       // A-row / C-col index (= px for B)
    const int h    = lane >> 5;       // k-slot half
    float* tr = trans[w];
    const ushort* xnB = (const ushort*)XN;
    const ushort* xrB = (const ushort*)XR;

    if (w < 3) {
        const ushort* ap0 = qkvw_b + ((size_t)(w * 64 + m)) * 256 + h * 8;
        const ushort* ap1 = ap0 + 32 * 256;
        f32x16 acc0, acc1;
        #pragma unroll
        for (int i = 0; i < 16; ++i) { acc0[i] = 0.f; acc1[i] = 0.f; }
        #pragma unroll 4
        for (int ks = 0; ks < 16; ++ks) {
            bf16x8 bf = *(const bf16x8*)(xnB + ((ks * 2 + h) * 32 + m) * 8);
            bf16x8 a0 = *(const bf16x8*)(ap0 + ks * 16);
            bf16x8 a1 = *(const bf16x8*)(ap1 + ks * 16);
            acc0 = __builtin_amdgcn_mfma_f32_32x32x16_bf16(a0, bf, acc0, 0, 0, 0);
            acc1 = __builtin_amdgcn_mfma_f32_32x32x16_bf16(a1, bf, acc1, 0, 0, 0);
        }
        for (int ti = 0; ti < 2; ++ti) {
            const f32x16& A = ti ? acc1 : acc0;
            #pragma unroll
            for (int r = 0; r < 16; ++r)
                tr[((r & 3) + 8 * (r >> 2) + 4 * h) * 33 + m] = A[r];
            if (w < 2) {
                ushort* dst = (w == 0) ? Qb : Kb;
                #pragma unroll
                for (int it = 0; it < 2; ++it) {
                    int unit = it * 2 + h;            // 0..3
                    int hl = unit >> 1, half = unit & 1;
                    float v0 = tr[(hl * 16 + half * 8 + 0) * 33 + m];
                    float v1 = tr[(hl * 16 + half * 8 + 1) * 33 + m];
                    float v2 = tr[(hl * 16 + half * 8 + 2) * 33 + m];
                    float v3 = tr[(hl * 16 + half * 8 + 3) * 33 + m];
                    float v4 = tr[(hl * 16 + half * 8 + 4) * 33 + m];
                    float v5 = tr[(hl * 16 + half * 8 + 5) * 33 + m];
                    float v6 = tr[(hl * 16 + half * 8 + 6) * 33 + m];
                    float v7 = tr[(hl * 16 + half * 8 + 7) * 33 + m];
                    uint4 pk;
                    pk.x = pack_bf(v0, v1); pk.y = pack_bf(v2, v3);
                    pk.z = pack_bf(v4, v5); pk.w = pack_bf(v6, v7);
                    int head = ti * 2 + hl;
                    *(uint4*)(dst + ((size_t)(b * 4 + head) * 4096 + n0 + m) * 16 + half * 8) = pk;
                }
            } else {
                int d = lane & 15, u = lane >> 4;
                #pragma unroll
                for (int it = 0; it < 4; ++it) {
                    int unit = it * 4 + u;            // 0..15
                    int hl = unit >> 3, sg = unit & 7;
                    float v0 = tr[(hl * 16 + d) * 33 + sg * 4 + 0];
                    float v1 = tr[(hl * 16 + d) * 33 + sg * 4 + 1];
                    float v2 = tr[(hl * 16 + d) * 33 + sg * 4 + 2];
                    float v3 = tr[(hl * 16 + d) * 33 + sg * 4 + 3];
                    uint2 pk; pk.x = pack_bf(v0, v1); pk.y = pack_bf(v2, v3);
                    int head = ti * 2 + hl;
                    *(uint2*)(Vsw + (((size_t)(b * 4 + head) * 1024 + (pg & 127) * 8 + sg) * 16 + d) * 4) = pk;
                }
            }
        }
    } else {
        // conv branch: 4 tiles x 16 ksteps on raw x (from LDS)
        f32x16 acc[4];
        #pragma unroll
        for (int ti = 0; ti < 4; ++ti)
            #pragma unroll
            for (int i = 0; i < 16; ++i) acc[ti][i] = 0.f;
        #pragma unroll 2
        for (int ks = 0; ks < 16; ++ks) {
            bf16x8 bf = *(const bf16x8*)(xrB + ((ks * 2 + h) * 32 + m) * 8);
            #pragma unroll
            for (int ti = 0; ti < 4; ++ti) {
                bf16x8 a = *(const bf16x8*)(c1w_b + ((size_t)(ti * 32 + m)) * 256 + ks * 16 + h * 8);
                acc[ti] = __builtin_amdgcn_mfma_f32_32x32x16_bf16(a, bf, acc[ti], 0, 0, 0);
            }
        }
        float partial = 0.f;
        for (int ti = 0; ti < 4; ++ti) {
            #pragma unroll
            for (int r = 0; r < 16; ++r)
                tr[((r & 3) + 8 * (r >> 2) + 4 * h) * 33 + m] = acc[ti][r];
            #pragma unroll
            for (int i = 0; i < 16; ++i) {
                int og = ti * 32 + h * 16 + i;
                partial += fmaxf(tr[(h * 16 + i) * 33 + m] + c1b[og], 0.f) * c2w[og];
            }
        }
        float tot = partial + __shfl_xor(partial, 32);
        if (lane < 32) dynb[(size_t)b * 4096 + n0 + m] = c2b[0] + tot;
    }
}

// ---------------------------------------------------------------------------
// attn_final: FUSED flash attention + merge + out-proj + sigmoid residual.
// One block = one 32-px group, 8 waves = (4 heads) x (2 key-halves kb).
// Each wave runs the 64-iter flash chain (identical to old attn), dumps
// O[16d][32px] + l into LDS. After barrier: 8 waves x 32 out-channels each:
// B-frag built from LDS (merge kb, /l, *dyn), A = out_w bf16, 4 ksteps
// (= heads). Epilogue via wave-private stride-33 LDS transpose ->
// coalesced sigmoid(g*y + x) writes. grid 256 x 512.
// ---------------------------------------------------------------------------
__global__ __launch_bounds__(512) void attn_final_kernel(
    const ushort* __restrict__ Qb, const ushort* __restrict__ Kb,
    const ushort* __restrict__ Vsw, const float* __restrict__ dynb,
    const ushort* __restrict__ ow_b, const float* __restrict__ x,
    const float* __restrict__ gamma, float* __restrict__ out)
{
    __shared__ float OM[2][4][16][32];   // [kb][head][d][px]  16 KB
    __shared__ float LM[2][4][32];       // [kb][head][px]      1 KB
    __shared__ float trans[8][32 * 33];  //                    33.8 KB

    const int t    = threadIdx.x;
    const int w    = t >> 6;          // 0..7
    const int lane = t & 63;
    const int c    = lane & 31;       // px within group (chain) / px col & A-row (gemm)
    const int h    = lane >> 5;
    const int hd   = w & 3;           // head
    const int kb   = w >> 2;          // key-half
    const int pg   = blockIdx.x;
    const int b    = pg >> 7;
    const int n0   = (pg & 127) * 32;
    const int bh   = b * 4 + hd;

    // ---------------- flash chain (identical math to old attn) ----------------
    const bf16x8 qf = *(const bf16x8*)(Qb + ((size_t)bh * 4096 + n0 + c) * 16 + h * 8);

    f32x16 oacc, zf;
    #pragma unroll
    for (int i = 0; i < 16; ++i) { oacc[i] = 0.f; zf[i] = 0.f; }

    const ushort* kp = Kb + ((size_t)bh * 4096 + kb * 2048 + c) * 16 + h * 8;
    const ushort* vb = Vsw + (size_t)bh * 65536 + ((size_t)kb * 512 + h) * 64 + c * 4;

    #pragma unroll 2
    for (int ch = 0; ch < 64; ++ch) {
        const bf16x8 kf = *(const bf16x8*)kp;
        f32x16 s = __builtin_amdgcn_mfma_f32_32x32x16_bf16(kf, qf, zf, 0, 0, 0);

        BF8 p1, p2;
        #pragma unroll
        for (int jj = 0; jj < 4; ++jj) {
            p1.u[jj] = pack_bf(__builtin_amdgcn_exp2f(s[2*jj]),   __builtin_amdgcn_exp2f(s[2*jj+1]));
            p2.u[jj] = pack_bf(__builtin_amdgcn_exp2f(s[8+2*jj]), __builtin_amdgcn_exp2f(s[8+2*jj+1]));
        }

        BF8 a1, a2;
        if (c < 16) {
            const uint2 g1 = *(const uint2*)(vb);
            const uint2 g2 = *(const uint2*)(vb + 128);
            const uint2 g3 = *(const uint2*)(vb + 256);
            const uint2 g4 = *(const uint2*)(vb + 384);
            a1.u[0] = g1.x; a1.u[1] = g1.y; a1.u[2] = g2.x; a1.u[3] = g2.y;
            a2.u[0] = g3.x; a2.u[1] = g3.y; a2.u[2] = g4.x; a2.u[3] = g4.y;
        } else {
            const uint f = (c == 16) ? 0x3F803F80u : 0u;   // ones row -> l
            a1.u[0] = a1.u[1] = a1.u[2] = a1.u[3] = f;
            a2.u[0] = a2.u[1] = a2.u[2] = a2.u[3] = f;
        }

        oacc = __builtin_amdgcn_mfma_f32_32x32x16_bf16(a1.v, p1.v, oacc, 0, 0, 0);
        oacc = __builtin_amdgcn_mfma_f32_32x32x16_bf16(a2.v, p2.v, oacc, 0, 0, 0);

        kp += 512; vb += 512;
    }

    // ---------------- merge into LDS ----------------
    // oacc reg r (0..7) holds output row d = (r&3)+8*(r>>2)+4h for px col c;
    // oacc[8] at h==0 holds row 16 = l.
    #pragma unroll
    for (int r = 0; r < 8; ++r)
        OM[kb][hd][(r & 3) + 8 * (r >> 2) + 4 * h][c] = oacc[r];
    if (h == 0) LM[kb][hd][c] = oacc[8];
    __syncthreads();

    // ---------------- out-proj GEMM: wave w -> channels w*32..w*32+31 ----------
    const int m = c;                              // px col = A row index
    const float dyn_px = dynb[(size_t)b * 4096 + n0 + m];

    f32x16 acc;
    #pragma unroll
    for (int i = 0; i < 16; ++i) acc[i] = 0.f;

    #pragma unroll
    for (int ks = 0; ks < 4; ++ks) {              // kstep = head
        float l   = LM[0][ks][m] + LM[1][ks][m];
        float fac = dyn_px / l;
        BF8 bfr;
        #pragma unroll
        for (int i = 0; i < 4; ++i) {
            int d0 = h * 8 + 2 * i;
            float e0 = (OM[0][ks][d0][m]     + OM[1][ks][d0][m])     * fac;
            float e1 = (OM[0][ks][d0 + 1][m] + OM[1][ks][d0 + 1][m]) * fac;
            bfr.u[i] = pack_bf(e0, e1);
        }
        bf16x8 af = *(const bf16x8*)(ow_b + (size_t)(w * 32 + m) * 64 + ks * 16 + h * 8);
        acc = __builtin_amdgcn_mfma_f32_32x32x16_bf16(af, bfr.v, acc, 0, 0, 0);
    }

    // ---------------- epilogue: transpose + sigmoid residual ----------------
    float* tr = trans[w];
    const float g = gamma[0];
    #pragma unroll
    for (int r = 0; r < 16; ++r)
        tr[((r & 3) + 8 * (r >> 2) + 4 * h) * 33 + m] = acc[r];
    #pragma unroll 4
    for (int it = 0; it < 16; ++it) {
        int o = it * 2 + h;                       // out channel within tile
        float vv = tr[o * 33 + m];
        size_t idx = ((size_t)b * 256 + w * 32 + o) * 4096 + n0 + m;
        float z = g * vv + x[idx];
        out[idx] = 1.f / (1.f + __builtin_amdgcn_exp2f(-z * LOG2E));
    }
}

// ---------------------------------------------------------------------------
extern "C" void kernel_launch(void* const* d_in, const int* in_sizes, int n_in,
                              void* d_out, int out_size, void* d_ws, size_t ws_size,
                              hipStream_t stream)
{
    const float* x      = (const float*)d_in[0];
    const float* norm_w = (const float*)d_in[1];
    const float* norm_b = (const float*)d_in[2];
    const float* qkv_w  = (const float*)d_in[3];
    const float* out_w  = (const float*)d_in[4];
    const float* c1w    = (const float*)d_in[5];
    const float* c1b    = (const float*)d_in[6];
    const float* c2w    = (const float*)d_in[7];
    const float* c2b    = (const float*)d_in[8];
    const float* gamma  = (const float*)d_in[9];

    char* ws = (char*)d_ws;
    ushort* Qb     = (ushort*)ws;                       // 524288 ush (1 MB)
    ushort* Kb     = Qb + 524288;
    ushort* Vsw    = Kb + 524288;                       // 524288 ush
    ushort* qkvw_b = Vsw + 524288;                      // 49152
    ushort* c1w_b  = qkvw_b + 49152;                    // 32768
    ushort* ow_b   = c1w_b + 32768;                     // 16384
    float*  dynb   = (float*)(ws + 3342336);            // 8192 floats

    hipLaunchKernelGGL(convert_w_kernel, dim3(96), dim3(256), 0, stream,
                       qkv_w, c1w, out_w, qkvw_b, c1w_b, ow_b);
    hipLaunchKernelGGL(lnqkv_kernel, dim3(256), dim3(256), 0, stream,
                       x, norm_w, norm_b, qkvw_b, c1w_b, c1b, c2w, c2b,
                       Qb, Kb, Vsw, dynb);
    hipLaunchKernelGGL(attn_final_kernel, dim3(256), dim3(512), 0, stream,
                       Qb, Kb, Vsw, dynb, ow_b, x, gamma, (float*)d_out);
}

// Round 3
// 114.460 us; speedup vs baseline: 1.2186x; 1.0935x over previous
//
#include <hip/hip_runtime.h>
#include <cstdint>
#include <cstddef>

#define LOG2E 1.44269504088896340736f

typedef float  f32x16 __attribute__((ext_vector_type(16)));
typedef __bf16 bf16x8 __attribute__((ext_vector_type(8)));

union BF8 { bf16x8 v; uint u[4]; ushort us[8]; };

// pack two floats to bf16 pair (round-half-up), a -> lo16, b -> hi16
__device__ __forceinline__ uint pack_bf(float a, float b) {
    uint ua = __float_as_uint(a) + 0x8000u;
    uint ub = __float_as_uint(b) + 0x8000u;
    return __builtin_amdgcn_perm(ub, ua, 0x07060302u);
}
__device__ __forceinline__ float bf_lo(uint u) { return __uint_as_float(u << 16); }
__device__ __forceinline__ float bf_hi(uint u) { return __uint_as_float(u & 0xFFFF0000u); }

// ---------------------------------------------------------------------------
// convert_w: fp32 -> bf16 weights. qkv_w rows o<64 (=Q) pre-scaled 0.25*log2e.
// concat layout: qkv_w[49152] | c1w[32768] | out_w[16384] = 98304 elems.
// grid 96 x 256, one float4 per thread.
// ---------------------------------------------------------------------------
__global__ __launch_bounds__(256) void convert_w_kernel(
    const float* __restrict__ qkv_w, const float* __restrict__ c1w,
    const float* __restrict__ out_w,
    ushort* __restrict__ qkvw_b, ushort* __restrict__ c1w_b, ushort* __restrict__ ow_b)
{
    const int g = (blockIdx.x * 256 + threadIdx.x) * 4;
    const float* src; ushort* dst; int off; float sc = 1.f;
    if (g < 49152)      { src = qkv_w; dst = qkvw_b; off = g;
                          if (g < 16384) sc = 0.25f * LOG2E; }
    else if (g < 81920) { src = c1w;   dst = c1w_b;  off = g - 49152; }
    else                { src = out_w; dst = ow_b;   off = g - 81920; }
    float4 v = *(const float4*)(src + off);
    uint2 pk;
    pk.x = pack_bf(v.x * sc, v.y * sc);
    pk.y = pack_bf(v.z * sc, v.w * sc);
    *(uint2*)(dst + off) = pk;
}

// ---------------------------------------------------------------------------
// lnqkv: FUSED LayerNorm + QKV/conv MFMA GEMMs. One block = one 32-px group.
// Phase 1: per-px LayerNorm over 256 ch; xn (normalized) and xr (raw) land in
//   LDS in B-fragment-major layout [u=c/8][px][8ch] bf16 -> the MFMA loop's
//   B-load is a wave-contiguous ds_read_b128 (1 KB/wave, conflict-free).
// Phase 2: 4 waves: w0/1/2 = Q/K/V (2 tiles each, A=weights), w3 = conv
//   branch (4 tiles, B=xr) with relu*c2w reduction -> dynb.
// Epilogues via wave-private LDS transpose (stride 33, conflict-free).
// grid 256 x 256.
// ---------------------------------------------------------------------------
__global__ __launch_bounds__(256) void lnqkv_kernel(
    const float* __restrict__ x, const float* __restrict__ nw, const float* __restrict__ nb,
    const ushort* __restrict__ qkvw_b, const ushort* __restrict__ c1w_b,
    const float* __restrict__ c1b, const float* __restrict__ c2w,
    const float* __restrict__ c2b,
    ushort* __restrict__ Qb, ushort* __restrict__ Kb, ushort* __restrict__ Vsw,
    float* __restrict__ dynb)
{
    __shared__ uint  XN[32 * 32 * 4];      // [u][px][4 uint=8 bf16]  16 KB
    __shared__ uint  XR[32 * 32 * 4];      // raw x, same layout      16 KB
    __shared__ float trans[4][32 * 33];    //                         16.9 KB
    __shared__ float red1[256], red2[256];
    __shared__ float muS[32], rsS[32];

    const int t    = threadIdx.x;
    const int pg   = blockIdx.x;
    const int b    = pg >> 7;
    const int n0   = (pg & 127) * 32;

    // ------------------ Phase 1: LayerNorm into LDS ------------------
    {
        const int j  = t & 31;            // px
        const int cg = t >> 5;            // channel group (32 ch each)
        const size_t xb = (size_t)b * 256 * 4096 + n0 + j;
        float v[32];
        #pragma unroll
        for (int i = 0; i < 32; ++i) v[i] = x[xb + (size_t)(cg * 32 + i) * 4096];
        float s1 = 0.f, s2 = 0.f;
        #pragma unroll
        for (int i = 0; i < 32; ++i) { s1 += v[i]; s2 += v[i] * v[i]; }
        // raw x bf16 -> XR  (chunk u = cg*4+kk, px j); wave pattern is
        // 512B-sequential per 32-lane half -> conflict-free
        #pragma unroll
        for (int kk = 0; kk < 4; ++kk) {
            uint4 pk;
            pk.x = pack_bf(v[kk * 8 + 0], v[kk * 8 + 1]);
            pk.y = pack_bf(v[kk * 8 + 2], v[kk * 8 + 3]);
            pk.z = pack_bf(v[kk * 8 + 4], v[kk * 8 + 5]);
            pk.w = pack_bf(v[kk * 8 + 6], v[kk * 8 + 7]);
            *(uint4*)&XR[((cg * 4 + kk) * 32 + j) * 4] = pk;
        }
        red1[t] = s1; red2[t] = s2;
        __syncthreads();
        if (t < 32) {
            float a = 0.f, q = 0.f;
            #pragma unroll
            for (int g2 = 0; g2 < 8; ++g2) { a += red1[g2 * 32 + t]; q += red2[g2 * 32 + t]; }
            float mu  = a * (1.f / 256.f);
            float var = q * (1.f / 256.f) - mu * mu;
            muS[t] = mu; rsS[t] = rsqrtf(fmaxf(var, 0.f) + 1e-5f);
        }
        __syncthreads();
        const float mu = muS[j], rs = rsS[j];
        #pragma unroll
        for (int kk = 0; kk < 4; ++kk) {
            const float4 w0 = *(const float4*)(nw + cg * 32 + kk * 8);
            const float4 w1 = *(const float4*)(nw + cg * 32 + kk * 8 + 4);
            const float4 b0 = *(const float4*)(nb + cg * 32 + kk * 8);
            const float4 b1 = *(const float4*)(nb + cg * 32 + kk * 8 + 4);
            float e0 = (v[kk * 8 + 0] - mu) * rs * w0.x + b0.x;
            float e1 = (v[kk * 8 + 1] - mu) * rs * w0.y + b0.y;
            float e2 = (v[kk * 8 + 2] - mu) * rs * w0.z + b0.z;
            float e3 = (v[kk * 8 + 3] - mu) * rs * w0.w + b0.w;
            float e4 = (v[kk * 8 + 4] - mu) * rs * w1.x + b1.x;
            float e5 = (v[kk * 8 + 5] - mu) * rs * w1.y + b1.y;
            float e6 = (v[kk * 8 + 6] - mu) * rs * w1.z + b1.z;
            float e7 = (v[kk * 8 + 7] - mu) * rs * w1.w + b1.w;
            uint4 o;
            o.x = pack_bf(e0, e1); o.y = pack_bf(e2, e3);
            o.z = pack_bf(e4, e5); o.w = pack_bf(e6, e7);
            *(uint4*)&XN[((cg * 4 + kk) * 32 + j) * 4] = o;
        }
    }
    __syncthreads();

    // ------------------ Phase 2: MFMA GEMMs from LDS ------------------
    const int w    = t >> 6;
    const int lane = t & 63;
    const int m    = lane & 31;       // A-row / C-col index (= px for B)
    const int h    = lane >> 5;       // k-slot half
    float* tr = trans[w];
    const ushort* xnB = (const ushort*)XN;
    const ushort* xrB = (const ushort*)XR;

    if (w < 3) {
        const ushort* ap0 = qkvw_b + ((size_t)(w * 64 + m)) * 256 + h * 8;
        const ushort* ap1 = ap0 + 32 * 256;
        f32x16 acc0, acc1;
        #pragma unroll
        for (int i = 0; i < 16; ++i) { acc0[i] = 0.f; acc1[i] = 0.f; }
        #pragma unroll 4
        for (int ks = 0; ks < 16; ++ks) {
            bf16x8 bf = *(const bf16x8*)(xnB + ((ks * 2 + h) * 32 + m) * 8);
            bf16x8 a0 = *(const bf16x8*)(ap0 + ks * 16);
            bf16x8 a1 = *(const bf16x8*)(ap1 + ks * 16);
            acc0 = __builtin_amdgcn_mfma_f32_32x32x16_bf16(a0, bf, acc0, 0, 0, 0);
            acc1 = __builtin_amdgcn_mfma_f32_32x32x16_bf16(a1, bf, acc1, 0, 0, 0);
        }
        for (int ti = 0; ti < 2; ++ti) {
            const f32x16& A = ti ? acc1 : acc0;
            #pragma unroll
            for (int r = 0; r < 16; ++r)
                tr[((r & 3) + 8 * (r >> 2) + 4 * h) * 33 + m] = A[r];
            if (w < 2) {
                ushort* dst = (w == 0) ? Qb : Kb;
                #pragma unroll
                for (int it = 0; it < 2; ++it) {
                    int unit = it * 2 + h;            // 0..3
                    int hl = unit >> 1, half = unit & 1;
                    float v0 = tr[(hl * 16 + half * 8 + 0) * 33 + m];
                    float v1 = tr[(hl * 16 + half * 8 + 1) * 33 + m];
                    float v2 = tr[(hl * 16 + half * 8 + 2) * 33 + m];
                    float v3 = tr[(hl * 16 + half * 8 + 3) * 33 + m];
                    float v4 = tr[(hl * 16 + half * 8 + 4) * 33 + m];
                    float v5 = tr[(hl * 16 + half * 8 + 5) * 33 + m];
                    float v6 = tr[(hl * 16 + half * 8 + 6) * 33 + m];
                    float v7 = tr[(hl * 16 + half * 8 + 7) * 33 + m];
                    uint4 pk;
                    pk.x = pack_bf(v0, v1); pk.y = pack_bf(v2, v3);
                    pk.z = pack_bf(v4, v5); pk.w = pack_bf(v6, v7);
                    int head = ti * 2 + hl;
                    *(uint4*)(dst + ((size_t)(b * 4 + head) * 4096 + n0 + m) * 16 + half * 8) = pk;
                }
            } else {
                int d = lane & 15, u = lane >> 4;
                #pragma unroll
                for (int it = 0; it < 4; ++it) {
                    int unit = it * 4 + u;            // 0..15
                    int hl = unit >> 3, sg = unit & 7;
                    float v0 = tr[(hl * 16 + d) * 33 + sg * 4 + 0];
                    float v1 = tr[(hl * 16 + d) * 33 + sg * 4 + 1];
                    float v2 = tr[(hl * 16 + d) * 33 + sg * 4 + 2];
                    float v3 = tr[(hl * 16 + d) * 33 + sg * 4 + 3];
                    uint2 pk; pk.x = pack_bf(v0, v1); pk.y = pack_bf(v2, v3);
                    int head = ti * 2 + hl;
                    *(uint2*)(Vsw + (((size_t)(b * 4 + head) * 1024 + (pg & 127) * 8 + sg) * 16 + d) * 4) = pk;
                }
            }
        }
    } else {
        // conv branch: 4 tiles x 16 ksteps on raw x (from LDS)
        f32x16 acc[4];
        #pragma unroll
        for (int ti = 0; ti < 4; ++ti)
            #pragma unroll
            for (int i = 0; i < 16; ++i) acc[ti][i] = 0.f;
        #pragma unroll 2
        for (int ks = 0; ks < 16; ++ks) {
            bf16x8 bf = *(const bf16x8*)(xrB + ((ks * 2 + h) * 32 + m) * 8);
            #pragma unroll
            for (int ti = 0; ti < 4; ++ti) {
                bf16x8 a = *(const bf16x8*)(c1w_b + ((size_t)(ti * 32 + m)) * 256 + ks * 16 + h * 8);
                acc[ti] = __builtin_amdgcn_mfma_f32_32x32x16_bf16(a, bf, acc[ti], 0, 0, 0);
            }
        }
        float partial = 0.f;
        for (int ti = 0; ti < 4; ++ti) {
            #pragma unroll
            for (int r = 0; r < 16; ++r)
                tr[((r & 3) + 8 * (r >> 2) + 4 * h) * 33 + m] = acc[ti][r];
            #pragma unroll
            for (int i = 0; i < 16; ++i) {
                int og = ti * 32 + h * 16 + i;
                partial += fmaxf(tr[(h * 16 + i) * 33 + m] + c1b[og], 0.f) * c2w[og];
            }
        }
        float tot = partial + __shfl_xor(partial, 32);
        if (lane < 32) dynb[(size_t)b * 4096 + n0 + m] = c2b[0] + tot;
    }
}

// ---------------------------------------------------------------------------
// attn_final: FUSED flash attention + merge + out-proj + sigmoid residual.
// One block = one 32-px group, 16 waves = (4 heads) x (4 key-quarters kb).
// Each wave runs a 32-iter flash chain (4 waves/SIMD occupancy, chains half
// the length of R2), dumps O rows (float2-paired) + l into LDS. After one
// barrier: waves 0-7 each produce 32 out-channels: B-frag built from LDS
// (merge 4 kb, /l, *dyn), A = out_w bf16, 4 ksteps (= heads). Epilogue
// stores acc directly (same 2x128B coalescing as a transpose would give).
// grid 256 x 1024.
// ---------------------------------------------------------------------------
__global__ __launch_bounds__(1024) void attn_final_kernel(
    const ushort* __restrict__ Qb, const ushort* __restrict__ Kb,
    const ushort* __restrict__ Vsw, const float* __restrict__ dynb,
    const ushort* __restrict__ ow_b, const float* __restrict__ x,
    const float* __restrict__ gamma, float* __restrict__ out)
{
    __shared__ float2 OM[4][4][8][32];   // [kb][head][d/2][px]  32 KB
    __shared__ float  LM[4][4][32];      // [kb][head][px]        2 KB

    const int t    = threadIdx.x;
    const int w    = t >> 6;          // 0..15
    const int lane = t & 63;
    const int c    = lane & 31;       // px within group / A-row (gemm)
    const int h    = lane >> 5;
    const int hd   = w & 3;           // head
    const int kb   = w >> 2;          // key-quarter (0..3)
    const int pg   = blockIdx.x;
    const int b    = pg >> 7;
    const int n0   = (pg & 127) * 32;
    const int bh   = b * 4 + hd;

    // ---------------- flash chain: 32 iters over this key-quarter ----------------
    const bf16x8 qf = *(const bf16x8*)(Qb + ((size_t)bh * 4096 + n0 + c) * 16 + h * 8);

    f32x16 oacc, zf;
    #pragma unroll
    for (int i = 0; i < 16; ++i) { oacc[i] = 0.f; zf[i] = 0.f; }

    const ushort* kp = Kb + ((size_t)bh * 4096 + kb * 1024 + c) * 16 + h * 8;
    const ushort* vb = Vsw + (size_t)bh * 65536 + ((size_t)kb * 256 + h) * 64 + c * 4;

    #pragma unroll 2
    for (int ch = 0; ch < 32; ++ch) {
        const bf16x8 kf = *(const bf16x8*)kp;
        f32x16 s = __builtin_amdgcn_mfma_f32_32x32x16_bf16(kf, qf, zf, 0, 0, 0);

        BF8 p1, p2;
        #pragma unroll
        for (int jj = 0; jj < 4; ++jj) {
            p1.u[jj] = pack_bf(__builtin_amdgcn_exp2f(s[2*jj]),   __builtin_amdgcn_exp2f(s[2*jj+1]));
            p2.u[jj] = pack_bf(__builtin_amdgcn_exp2f(s[8+2*jj]), __builtin_amdgcn_exp2f(s[8+2*jj+1]));
        }

        BF8 a1, a2;
        if (c < 16) {
            const uint2 g1 = *(const uint2*)(vb);
            const uint2 g2 = *(const uint2*)(vb + 128);
            const uint2 g3 = *(const uint2*)(vb + 256);
            const uint2 g4 = *(const uint2*)(vb + 384);
            a1.u[0] = g1.x; a1.u[1] = g1.y; a1.u[2] = g2.x; a1.u[3] = g2.y;
            a2.u[0] = g3.x; a2.u[1] = g3.y; a2.u[2] = g4.x; a2.u[3] = g4.y;
        } else {
            const uint f = (c == 16) ? 0x3F803F80u : 0u;   // ones row -> l
            a1.u[0] = a1.u[1] = a1.u[2] = a1.u[3] = f;
            a2.u[0] = a2.u[1] = a2.u[2] = a2.u[3] = f;
        }

        oacc = __builtin_amdgcn_mfma_f32_32x32x16_bf16(a1.v, p1.v, oacc, 0, 0, 0);
        oacc = __builtin_amdgcn_mfma_f32_32x32x16_bf16(a2.v, p2.v, oacc, 0, 0, 0);

        kp += 512; vb += 512;
    }

    // ---------------- merge into LDS ----------------
    // oacc reg r (0..7) holds output row d = (r&3)+8*(r>>2)+4h for px col c;
    // paired as float2 per even d. oacc[8] at h==0 holds row 16 = l.
    OM[kb][hd][2 * h + 0][c] = make_float2(oacc[0], oacc[1]);
    OM[kb][hd][2 * h + 1][c] = make_float2(oacc[2], oacc[3]);
    OM[kb][hd][4 + 2 * h][c] = make_float2(oacc[4], oacc[5]);
    OM[kb][hd][5 + 2 * h][c] = make_float2(oacc[6], oacc[7]);
    if (h == 0) LM[kb][hd][c] = oacc[8];
    __syncthreads();

    // ---------------- out-proj GEMM: waves 0-7 -> channels w*32..w*32+31 --------
    if (w < 8) {
        const int m = c;                              // px col = A row index
        const float dyn_px = dynb[(size_t)b * 4096 + n0 + m];

        f32x16 acc;
        #pragma unroll
        for (int i = 0; i < 16; ++i) acc[i] = 0.f;

        #pragma unroll
        for (int ks = 0; ks < 4; ++ks) {              // kstep = head
            float l = LM[0][ks][m] + LM[1][ks][m] + LM[2][ks][m] + LM[3][ks][m];
            float fac = dyn_px / l;
            BF8 bfr;
            #pragma unroll
            for (int i = 0; i < 4; ++i) {
                int sl = 4 * h + i;                   // d-pair slot = (h*8+2i)/2
                float2 s0 = OM[0][ks][sl][m];
                float2 s1 = OM[1][ks][sl][m];
                float2 s2 = OM[2][ks][sl][m];
                float2 s3 = OM[3][ks][sl][m];
                float e0 = (s0.x + s1.x + s2.x + s3.x) * fac;
                float e1 = (s0.y + s1.y + s2.y + s3.y) * fac;
                bfr.u[i] = pack_bf(e0, e1);
            }
            bf16x8 af = *(const bf16x8*)(ow_b + (size_t)(w * 32 + m) * 64 + ks * 16 + h * 8);
            acc = __builtin_amdgcn_mfma_f32_32x32x16_bf16(af, bfr.v, acc, 0, 0, 0);
        }

        // ------- epilogue: direct store (2x128B segments per r, coalesced) ------
        const float g = gamma[0];
        #pragma unroll
        for (int r = 0; r < 16; ++r) {
            int o = (r & 3) + 8 * (r >> 2) + 4 * h;   // out channel within tile
            size_t idx = ((size_t)b * 256 + w * 32 + o) * 4096 + n0 + m;
            float z = g * acc[r] + x[idx];
            out[idx] = 1.f / (1.f + __builtin_amdgcn_exp2f(-z * LOG2E));
        }
    }
}

// ---------------------------------------------------------------------------
extern "C" void kernel_launch(void* const* d_in, const int* in_sizes, int n_in,
                              void* d_out, int out_size, void* d_ws, size_t ws_size,
                              hipStream_t stream)
{
    const float* x      = (const float*)d_in[0];
    const float* norm_w = (const float*)d_in[1];
    const float* norm_b = (const float*)d_in[2];
    const float* qkv_w  = (const float*)d_in[3];
    const float* out_w  = (const float*)d_in[4];
    const float* c1w    = (const float*)d_in[5];
    const float* c1b    = (const float*)d_in[6];
    const float* c2w    = (const float*)d_in[7];
    const float* c2b    = (const float*)d_in[8];
    const float* gamma  = (const float*)d_in[9];

    char* ws = (char*)d_ws;
    ushort* Qb     = (ushort*)ws;                       // 524288 ush (1 MB)
    ushort* Kb     = Qb + 524288;
    ushort* Vsw    = Kb + 524288;                       // 524288 ush
    ushort* qkvw_b = Vsw + 524288;                      // 49152
    ushort* c1w_b  = qkvw_b + 49152;                    // 32768
    ushort* ow_b   = c1w_b + 32768;                     // 16384
    float*  dynb   = (float*)(ws + 3342336);            // 8192 floats

    hipLaunchKernelGGL(convert_w_kernel, dim3(96), dim3(256), 0, stream,
                       qkv_w, c1w, out_w, qkvw_b, c1w_b, ow_b);
    hipLaunchKernelGGL(lnqkv_kernel, dim3(256), dim3(256), 0, stream,
                       x, norm_w, norm_b, qkvw_b, c1w_b, c1b, c2w, c2b,
                       Qb, Kb, Vsw, dynb);
    hipLaunchKernelGGL(attn_final_kernel, dim3(256), dim3(1024), 0, stream,
                       Qb, Kb, Vsw, dynb, ow_b, x, gamma, (float*)d_out);
}